// Round 2
// 4126.901 us; speedup vs baseline: 1.2599x; 1.2599x over previous
//
#include <hip/hip_runtime.h>
#include <math.h>

#define NBINS 131072

// ---- order-preserving float<->u32 encoding for atomicMax on floats ----
__device__ __forceinline__ unsigned encf(float f) {
    unsigned u = __float_as_uint(f);
    return (u & 0x80000000u) ? ~u : (u | 0x80000000u);
}
__device__ __forceinline__ float decf(unsigned u) {
    return (u & 0x80000000u) ? __uint_as_float(u & 0x7FFFFFFFu) : __uint_as_float(~u);
}

// K1: per-bin count + min-index (head) over all N points. c0 = code0 >> 3 < 2^17.
__global__ void k_hist(const int* __restrict__ scode, int* head_min, int* cnt, int N) {
    int i = blockIdx.x * blockDim.x + threadIdx.x;
    if (i >= N) return;
    int c0 = scode[i] >> 3;
    atomicMin(&head_min[c0], i);
    atomicAdd(&cnt[c0], 1);
}

// K2: single-block dual scan over 131072 bins:
//  - presence scan -> rank per bin, compact heads/counts
//  - count scan    -> per-bin segment start in cluster-sorted point order
// ALIASING: writes binstart into cnt[] (after reading it) and zeroes head_min[]
// (reused as the scatter fill counter) for nonempty bins.
__global__ void k_scan_compact(int* cnt, int* head_min,
                               int* rank, int* heads, int* countsC) {
    __shared__ int partp[1024];
    __shared__ int partc[1024];
    int t = threadIdx.x;
    const int per = NBINS / 1024;  // 128
    int base = t * per;
    int sp = 0, sc = 0;
    for (int j = 0; j < per; j++) { int c = cnt[base + j]; sp += (c > 0); sc += c; }
    partp[t] = sp;
    partc[t] = sc;
    __syncthreads();
    if (t == 0) {
        int rp = 0, rc = 0;
        for (int i = 0; i < 1024; i++) {
            int vp = partp[i], vc = partc[i];
            partp[i] = rp; partc[i] = rc;
            rp += vp; rc += vc;
        }
    }
    __syncthreads();
    int rp = partp[t], rc = partc[t];
    for (int j = 0; j < per; j++) {
        int v = base + j;
        int c = cnt[v];
        if (c > 0) {
            rank[v] = rp;
            heads[rp] = head_min[v];
            countsC[rp] = c;
            cnt[v] = rc;       // binstart (alias)
            head_min[v] = 0;   // fill3 init (alias)
            rp++;
            rc += c;
        }
    }
}

// K3: per-point cluster id output + coord sums (atomics) + cluster-sorted scatter.
__global__ void k_points(const int* __restrict__ scode, const int* __restrict__ rank,
                         const int* __restrict__ binstart, int* fill3,
                         const float* __restrict__ coord, float* __restrict__ cluster_out,
                         float* __restrict__ coordsum, int* __restrict__ sorted, int N) {
    int i = blockIdx.x * blockDim.x + threadIdx.x;
    if (i >= N) return;
    int bin = scode[i] >> 3;
    int m = rank[bin];
    cluster_out[i] = (float)m;
    int pos = binstart[bin] + atomicAdd(&fill3[bin], 1);
    sorted[pos] = i;
    atomicAdd(&coordsum[m * 3 + 0], coord[(size_t)i * 3 + 0]);
    atomicAdd(&coordsum[m * 3 + 1], coord[(size_t)i * 3 + 1]);
    atomicAdd(&coordsum[m * 3 + 2], coord[(size_t)i * 3 + 2]);
}

// K4: per-cluster small outputs + histogram of c1 buckets for the row-1 sort.
__global__ void k_clusters(const int* __restrict__ scode, const int* __restrict__ batch,
                           const int* __restrict__ grid_coord, const int* __restrict__ heads,
                           const int* __restrict__ countsC, const float* __restrict__ coordsum,
                           float* __restrict__ coord_p, float* __restrict__ grid_p,
                           float* __restrict__ code_h, float* __restrict__ order,
                           float* __restrict__ inverse, float* __restrict__ batch_p,
                           int* hist2, int M, int N) {
    int m = blockIdx.x * blockDim.x + threadIdx.x;
    if (m >= M) return;
    int h = heads[m];
    float invc = 1.0f / (float)countsC[m];
    coord_p[m * 3 + 0] = coordsum[m * 3 + 0] * invc;
    coord_p[m * 3 + 1] = coordsum[m * 3 + 1] * invc;
    coord_p[m * 3 + 2] = coordsum[m * 3 + 2] * invc;
    grid_p[m * 3 + 0] = (float)(grid_coord[(size_t)h * 3 + 0] >> 1);
    grid_p[m * 3 + 1] = (float)(grid_coord[(size_t)h * 3 + 1] >> 1);
    grid_p[m * 3 + 2] = (float)(grid_coord[(size_t)h * 3 + 2] >> 1);
    int c1 = scode[N + h] >> 3;
    code_h[m] = (float)(scode[h] >> 3);
    code_h[M + m] = (float)c1;
    // row 0 of code_h is strictly increasing in m -> order/inverse row 0 are identity
    order[m] = (float)m;
    inverse[m] = (float)m;
    batch_p[m] = (float)batch[h];
    atomicAdd(&hist2[c1 >> 10], 1);
}

// K5: in-place exclusive scan of the 2^17 bucket histogram (single block).
__global__ void k_scan_excl(int* a) {
    __shared__ int part[1024];
    int t = threadIdx.x;
    const int per = NBINS / 1024;
    int base = t * per;
    int s = 0;
    for (int j = 0; j < per; j++) s += a[base + j];
    part[t] = s;
    __syncthreads();
    if (t == 0) {
        int run = 0;
        for (int i = 0; i < 1024; i++) { int v = part[i]; part[i] = run; run += v; }
    }
    __syncthreads();
    int run = part[t];
    for (int j = 0; j < per; j++) { int v = a[base + j]; a[base + j] = run; run += v; }
}

// K6: scatter (c1_low<<17 | m) keys into buckets (bucket = c1>>10).
__global__ void k_keys(const int* __restrict__ scode, const int* __restrict__ heads,
                       const int* __restrict__ start, int* fill2, int* keys, int M, int N) {
    int m = blockIdx.x * blockDim.x + threadIdx.x;
    if (m >= M) return;
    int c1 = scode[N + heads[m]] >> 3;
    int b = c1 >> 10;
    int pos = start[b] + atomicAdd(&fill2[b], 1);
    keys[pos] = ((c1 & 1023) << 17) | m;
}

// K7: per-bucket insertion sort (bucket sizes ~Poisson(1), max ~10).
__global__ void k_bsort(int* keys, const int* __restrict__ start, const int* __restrict__ sz) {
    int b = blockIdx.x * blockDim.x + threadIdx.x;
    if (b >= NBINS) return;
    int s = start[b], n = sz[b];
    for (int i = 1; i < n; i++) {
        int k = keys[s + i];
        int j = i - 1;
        while (j >= 0 && keys[s + j] > k) { keys[s + j + 1] = keys[s + j]; j--; }
        keys[s + j + 1] = k;
    }
}

// K8: extract order row 1 and its inverse permutation.
__global__ void k_orders(const int* __restrict__ keys, float* __restrict__ order1,
                         float* __restrict__ inverse1, int M) {
    int i = blockIdx.x * blockDim.x + threadIdx.x;
    if (i >= M) return;
    int m = keys[i] & 0x1FFFF;
    order1[i] = (float)m;
    inverse1[m] = (float)i;
}

// K9: fp32 GEMM over CLUSTER-SORTED points, fused with segmented max.
// Block: 64 sorted points x 256 channels (4 serial 64-ch tiles), 256 threads, 4x4 blocking.
// Clusters are contiguous in the sorted order, so the per-tile epilogue max-reduces runs
// of equal cluster id in LDS: interior runs -> one coalesced plain store per cluster,
// quarter-boundary runs -> atomicMax. Replaces 256 atomics/point with ~0.03/point.
// sf uses an XOR column swizzle (col' = c4 ^ (row>>2)) so the fragment reads
// (rows pg*4+p at a shared k-column) spread across banks: 8-way conflict -> free 2-way.
__global__ __launch_bounds__(256) void k_gemm_max(
    const float* __restrict__ feat, const float* __restrict__ W, const float* __restrict__ bias,
    const int* __restrict__ scode, const int* __restrict__ rank, const int* __restrict__ sorted,
    unsigned* __restrict__ xout, int N) {
    __shared__ float sf[64][132];
    __shared__ float sw[64][132];  // doubles as the 64x64 proj tile in the epilogue
    __shared__ int scid[64];
    __shared__ int sidx[64];
    int t = threadIdx.x;
    int rowbase = blockIdx.x * 64;
    if (t < 64) {
        int i = sorted[rowbase + t];
        sidx[t] = i;
        scid[t] = rank[scode[i] >> 3];
    }
    __syncthreads();
    // stage 64x128 gathered feat rows (each row = contiguous 512B segment), XOR-swizzled cols
#pragma unroll
    for (int j = 0; j < 8; j++) {
        int idx = t + 256 * j;
        int r = idx >> 5, c4 = idx & 31;
        float4 v = *(const float4*)(feat + (size_t)sidx[r] * 128 + c4 * 4);
        *(float4*)&sf[r][((c4 ^ (r >> 2)) & 31) * 4] = v;
    }
    int pg = t & 15, cg = t >> 4;
    int q = t >> 6, ch = t & 63;  // epilogue roles: wave q scans points [16q,16q+16) for channel ch
    for (int ct = 0; ct < 4; ct++) {
        __syncthreads();  // protect sw restage vs previous epilogue (and sf/scid on first pass)
#pragma unroll
        for (int j = 0; j < 8; j++) {
            int idx = t + 256 * j;
            int r = idx >> 5, c4 = idx & 31;
            float4 v = *(const float4*)(W + (size_t)(ct * 64 + r) * 128 + c4 * 4);
            *(float4*)&sw[r][c4 * 4] = v;
        }
        __syncthreads();
        float acc[4][4] = {};
#pragma unroll
        for (int kc = 0; kc < 32; kc++) {
            float4 fv[4], wv[4];
            int kx = ((kc ^ pg) & 31) * 4;  // read feat k-col kc from swizzled storage
#pragma unroll
            for (int p = 0; p < 4; p++) fv[p] = *(const float4*)&sf[pg * 4 + p][kx];
#pragma unroll
            for (int c = 0; c < 4; c++) wv[c] = *(const float4*)&sw[cg * 4 + c][kc * 4];
#pragma unroll
            for (int p = 0; p < 4; p++)
#pragma unroll
                for (int c = 0; c < 4; c++)
                    acc[p][c] += fv[p].x * wv[c].x + fv[p].y * wv[c].y +
                                 fv[p].z * wv[c].z + fv[p].w * wv[c].w;
        }
        __syncthreads();  // all sw (W-tile) reads done
        // proj (+bias) -> sw as [point][ch_local]
        float b0 = bias[ct * 64 + cg * 4 + 0];
        float b1 = bias[ct * 64 + cg * 4 + 1];
        float b2 = bias[ct * 64 + cg * 4 + 2];
        float b3 = bias[ct * 64 + cg * 4 + 3];
#pragma unroll
        for (int p = 0; p < 4; p++) {
            float4 o = make_float4(acc[p][0] + b0, acc[p][1] + b1, acc[p][2] + b2, acc[p][3] + b3);
            *(float4*)&sw[pg * 4 + p][cg * 4] = o;
        }
        __syncthreads();
        // segmented max over the sorted 64-point tile; run boundaries are wave-uniform.
        // Runs strictly inside a 16-point quarter are complete clusters -> plain store
        // (all 64 lanes emit the same cid in the same iteration -> coalesced 256B).
        {
            int p0 = q * 16;
            int cur = scid[p0];
            float mx = sw[p0][ch];
            bool tstart = true;  // current run touches the quarter's start
            size_t choff = (size_t)(ct * 64 + ch);
            for (int p = 1; p < 16; p++) {
                int cid = scid[p0 + p];
                float v = sw[p0 + p][ch];
                if (cid == cur) {
                    mx = fmaxf(mx, v);
                } else {
                    unsigned e = encf(mx);
                    if (tstart) atomicMax(&xout[(size_t)cur * 256 + choff], e);
                    else xout[(size_t)cur * 256 + choff] = e;
                    tstart = false;
                    cur = cid;
                    mx = v;
                }
            }
            // final run touches the quarter's end -> may continue into next quarter/block
            atomicMax(&xout[(size_t)cur * 256 + choff], encf(mx));
        }
    }
}

// K10: in-place LayerNorm + exact GELU over each cluster row (decode encoded maxes first).
__global__ __launch_bounds__(256) void k_ln_gelu(unsigned* __restrict__ x,
                                                 const float* __restrict__ gamma,
                                                 const float* __restrict__ beta, int M) {
    int row = blockIdx.x;
    if (row >= M) return;
    int t = threadIdx.x;
    float v = decf(x[(size_t)row * 256 + t]);
    float s = v, s2 = v * v;
#pragma unroll
    for (int off = 32; off > 0; off >>= 1) {
        s += __shfl_down(s, off);
        s2 += __shfl_down(s2, off);
    }
    __shared__ float red[8];
    int wave = t >> 6, lane = t & 63;
    if (lane == 0) { red[wave] = s; red[4 + wave] = s2; }
    __syncthreads();
    if (t == 0) {
        red[0] = red[0] + red[1] + red[2] + red[3];
        red[4] = red[4] + red[5] + red[6] + red[7];
    }
    __syncthreads();
    float mean = red[0] * (1.0f / 256.0f);
    float var = red[4] * (1.0f / 256.0f) - mean * mean;
    float xn = (v - mean) * rsqrtf(var + 1e-5f) * gamma[t] + beta[t];
    float g = 0.5f * xn * (1.0f + erff(xn * 0.70710678118654752f));
    ((float*)x)[(size_t)row * 256 + t] = g;
}

extern "C" void kernel_launch(void* const* d_in, const int* in_sizes, int n_in,
                              void* d_out, int out_size, void* d_ws, size_t ws_size,
                              hipStream_t stream) {
    const float* feat = (const float*)d_in[0];
    const float* coord = (const float*)d_in[1];
    const int* grid_coord = (const int*)d_in[2];
    const int* scode = (const int*)d_in[3];   // int32 (JAX x64-off truncation), shape (2,N)
    const int* batch = (const int*)d_in[4];
    const float* W = (const float*)d_in[6];
    const float* bias = (const float*)d_in[7];
    const float* gamma = (const float*)d_in[8];
    const float* beta = (const float*)d_in[9];

    int N = in_sizes[0] / 128;                 // C_IN = 128
    int M = (out_size - N) / 269;              // 269 = 256+3+3+2+2+2+1 per-cluster elems

    float* out = (float*)d_out;
    float* x_out = out;                        // M*256
    float* coord_p = x_out + (size_t)M * 256;  // 3M
    float* grid_p = coord_p + (size_t)3 * M;   // 3M
    float* code_h = grid_p + (size_t)3 * M;    // 2M
    float* order = code_h + (size_t)2 * M;     // 2M
    float* inverse = order + (size_t)2 * M;    // 2M
    float* cluster = inverse + (size_t)2 * M;  // N
    float* batch_p = cluster + (size_t)N;      // M

    int* head_min = (int*)d_ws;        // NBINS  (reused as scatter fill counters)
    int* cnt = head_min + NBINS;       // NBINS  (reused as per-bin segment starts)
    int* rank = cnt + NBINS;           // NBINS
    int* hist2 = rank + NBINS;         // NBINS
    int* fill2 = hist2 + NBINS;        // NBINS
    int* heads = fill2 + NBINS;        // M
    int* countsC = heads + M;          // M
    float* coordsum = (float*)(countsC + M);       // 3M
    int* keys = (int*)(coordsum + (size_t)3 * M);  // M
    int* sorted = keys + M;                        // N (cluster-sorted point permutation)

    hipMemsetAsync(head_min, 0x7F, (size_t)NBINS * sizeof(int), stream);      // "+inf" index
    hipMemsetAsync(cnt, 0, (size_t)4 * NBINS * sizeof(int), stream);          // cnt,rank,hist2,fill2
    hipMemsetAsync(coordsum, 0, (size_t)3 * M * sizeof(float), stream);
    hipMemsetAsync(x_out, 0, (size_t)M * 256 * sizeof(float), stream);        // encoded -inf

    k_hist<<<(N + 255) / 256, 256, 0, stream>>>(scode, head_min, cnt, N);
    k_scan_compact<<<1, 1024, 0, stream>>>(cnt, head_min, rank, heads, countsC);
    k_points<<<(N + 255) / 256, 256, 0, stream>>>(scode, rank, cnt, head_min, coord, cluster,
                                                  coordsum, sorted, N);
    k_clusters<<<(M + 255) / 256, 256, 0, stream>>>(scode, batch, grid_coord, heads, countsC,
                                                    coordsum, coord_p, grid_p, code_h, order,
                                                    inverse, batch_p, hist2, M, N);
    k_scan_excl<<<1, 1024, 0, stream>>>(hist2);
    k_keys<<<(M + 255) / 256, 256, 0, stream>>>(scode, heads, hist2, fill2, keys, M, N);
    k_bsort<<<NBINS / 256, 256, 0, stream>>>(keys, hist2, fill2);
    k_orders<<<(M + 255) / 256, 256, 0, stream>>>(keys, order + M, inverse + M, M);
    k_gemm_max<<<N / 64, 256, 0, stream>>>(feat, W, bias, scode, rank, sorted,
                                           (unsigned*)x_out, N);
    k_ln_gelu<<<M, 256, 0, stream>>>((unsigned*)x_out, gamma, beta, M);
}

// Round 3
// 2251.921 us; speedup vs baseline: 2.3088x; 1.8326x over previous
//
#include <hip/hip_runtime.h>
#include <math.h>

#define NBINS 131072

typedef __attribute__((ext_vector_type(8))) short short8;
typedef __attribute__((ext_vector_type(4))) float f32x4;

// ---- order-preserving float<->u32 encoding for atomicMax on floats ----
__device__ __forceinline__ unsigned encf(float f) {
    unsigned u = __float_as_uint(f);
    return (u & 0x80000000u) ? ~u : (u | 0x80000000u);
}
__device__ __forceinline__ float decf(unsigned u) {
    return (u & 0x80000000u) ? __uint_as_float(u & 0x7FFFFFFFu) : __uint_as_float(~u);
}
// RNE fp32 -> bf16 (upper 16 bits)
__device__ __forceinline__ unsigned short bf16h(float f) {
    unsigned u = __float_as_uint(f);
    return (unsigned short)((u + 0x7FFFu + ((u >> 16) & 1u)) >> 16);
}

// K1: per-bin count + min-index (head) over all N points. c0 = code0 >> 3 < 2^17.
__global__ void k_hist(const int* __restrict__ scode, int* head_min, int* cnt, int N) {
    int i = blockIdx.x * blockDim.x + threadIdx.x;
    if (i >= N) return;
    int c0 = scode[i] >> 3;
    atomicMin(&head_min[c0], i);
    atomicAdd(&cnt[c0], 1);
}

// K2: single-block dual scan over 131072 bins (presence -> rank/compact; counts -> binstart).
// ALIASING: writes binstart into cnt[] and zeroes head_min[] (reused as scatter fill counter).
__global__ void k_scan_compact(int* cnt, int* head_min,
                               int* rank, int* heads, int* countsC) {
    __shared__ int partp[1024];
    __shared__ int partc[1024];
    int t = threadIdx.x;
    const int per = NBINS / 1024;  // 128
    int base = t * per;
    int sp = 0, sc = 0;
    for (int j = 0; j < per; j++) { int c = cnt[base + j]; sp += (c > 0); sc += c; }
    partp[t] = sp;
    partc[t] = sc;
    __syncthreads();
    if (t == 0) {
        int rp = 0, rc = 0;
        for (int i = 0; i < 1024; i++) {
            int vp = partp[i], vc = partc[i];
            partp[i] = rp; partc[i] = rc;
            rp += vp; rc += vc;
        }
    }
    __syncthreads();
    int rp = partp[t], rc = partc[t];
    for (int j = 0; j < per; j++) {
        int v = base + j;
        int c = cnt[v];
        if (c > 0) {
            rank[v] = rp;
            heads[rp] = head_min[v];
            countsC[rp] = c;
            cnt[v] = rc;       // binstart (alias)
            head_min[v] = 0;   // fill3 init (alias)
            rp++;
            rc += c;
        }
    }
}

// K3: per-point cluster id output + coord sums (atomics) + cluster-sorted scatter.
__global__ void k_points(const int* __restrict__ scode, const int* __restrict__ rank,
                         const int* __restrict__ binstart, int* fill3,
                         const float* __restrict__ coord, float* __restrict__ cluster_out,
                         float* __restrict__ coordsum, int* __restrict__ sorted, int N) {
    int i = blockIdx.x * blockDim.x + threadIdx.x;
    if (i >= N) return;
    int bin = scode[i] >> 3;
    int m = rank[bin];
    cluster_out[i] = (float)m;
    int pos = binstart[bin] + atomicAdd(&fill3[bin], 1);
    sorted[pos] = i;
    atomicAdd(&coordsum[m * 3 + 0], coord[(size_t)i * 3 + 0]);
    atomicAdd(&coordsum[m * 3 + 1], coord[(size_t)i * 3 + 1]);
    atomicAdd(&coordsum[m * 3 + 2], coord[(size_t)i * 3 + 2]);
}

// K3b: split W (256x128 fp32) into bf16 hi/lo for the Markidis 3-term MFMA GEMM.
// Whi/Wlo live in the dead head_min workspace region (free after k_points).
__global__ void k_wsplit(const float* __restrict__ W, unsigned short* __restrict__ Whi,
                         unsigned short* __restrict__ Wlo) {
    int i = blockIdx.x * blockDim.x + threadIdx.x;  // 32768 = 256*128
    float f = W[i];
    unsigned short h = bf16h(f);
    float hf = __uint_as_float((unsigned)h << 16);
    Whi[i] = h;
    Wlo[i] = bf16h(f - hf);
}

// K4: per-cluster small outputs + histogram of c1 buckets for the row-1 sort.
__global__ void k_clusters(const int* __restrict__ scode, const int* __restrict__ batch,
                           const int* __restrict__ grid_coord, const int* __restrict__ heads,
                           const int* __restrict__ countsC, const float* __restrict__ coordsum,
                           float* __restrict__ coord_p, float* __restrict__ grid_p,
                           float* __restrict__ code_h, float* __restrict__ order,
                           float* __restrict__ inverse, float* __restrict__ batch_p,
                           int* hist2, int M, int N) {
    int m = blockIdx.x * blockDim.x + threadIdx.x;
    if (m >= M) return;
    int h = heads[m];
    float invc = 1.0f / (float)countsC[m];
    coord_p[m * 3 + 0] = coordsum[m * 3 + 0] * invc;
    coord_p[m * 3 + 1] = coordsum[m * 3 + 1] * invc;
    coord_p[m * 3 + 2] = coordsum[m * 3 + 2] * invc;
    grid_p[m * 3 + 0] = (float)(grid_coord[(size_t)h * 3 + 0] >> 1);
    grid_p[m * 3 + 1] = (float)(grid_coord[(size_t)h * 3 + 1] >> 1);
    grid_p[m * 3 + 2] = (float)(grid_coord[(size_t)h * 3 + 2] >> 1);
    int c1 = scode[N + h] >> 3;
    code_h[m] = (float)(scode[h] >> 3);
    code_h[M + m] = (float)c1;
    // row 0 of code_h is strictly increasing in m -> order/inverse row 0 are identity
    order[m] = (float)m;
    inverse[m] = (float)m;
    batch_p[m] = (float)batch[h];
    atomicAdd(&hist2[c1 >> 10], 1);
}

// K5: in-place exclusive scan of the 2^17 bucket histogram (single block).
__global__ void k_scan_excl(int* a) {
    __shared__ int part[1024];
    int t = threadIdx.x;
    const int per = NBINS / 1024;
    int base = t * per;
    int s = 0;
    for (int j = 0; j < per; j++) s += a[base + j];
    part[t] = s;
    __syncthreads();
    if (t == 0) {
        int run = 0;
        for (int i = 0; i < 1024; i++) { int v = part[i]; part[i] = run; run += v; }
    }
    __syncthreads();
    int run = part[t];
    for (int j = 0; j < per; j++) { int v = a[base + j]; a[base + j] = run; run += v; }
}

// K6: scatter (c1_low<<17 | m) keys into buckets (bucket = c1>>10).
__global__ void k_keys(const int* __restrict__ scode, const int* __restrict__ heads,
                       const int* __restrict__ start, int* fill2, int* keys, int M, int N) {
    int m = blockIdx.x * blockDim.x + threadIdx.x;
    if (m >= M) return;
    int c1 = scode[N + heads[m]] >> 3;
    int b = c1 >> 10;
    int pos = start[b] + atomicAdd(&fill2[b], 1);
    keys[pos] = ((c1 & 1023) << 17) | m;
}

// K7: per-bucket insertion sort (bucket sizes ~Poisson(1), max ~10).
__global__ void k_bsort(int* keys, const int* __restrict__ start, const int* __restrict__ sz) {
    int b = blockIdx.x * blockDim.x + threadIdx.x;
    if (b >= NBINS) return;
    int s = start[b], n = sz[b];
    for (int i = 1; i < n; i++) {
        int k = keys[s + i];
        int j = i - 1;
        while (j >= 0 && keys[s + j] > k) { keys[s + j + 1] = keys[s + j]; j--; }
        keys[s + j + 1] = k;
    }
}

// K8: extract order row 1 and its inverse permutation.
__global__ void k_orders(const int* __restrict__ keys, float* __restrict__ order1,
                         float* __restrict__ inverse1, int M) {
    int i = blockIdx.x * blockDim.x + threadIdx.x;
    if (i >= M) return;
    int m = keys[i] & 0x1FFFF;
    order1[i] = (float)m;
    inverse1[m] = (float)i;
}

// K9: split-bf16 MFMA GEMM (proj = feat @ W^T + b as hi*hi + hi*lo + lo*hi, fp32 accum)
// over CLUSTER-SORTED points, fused with the segmented-max epilogue.
// Block: 64 points x 256 channels (4 serial 64-ch tiles), 256 threads = 4 waves.
// Wave w computes points [16w,16w+16) x all 64 chs of the tile via 4 mfma_f32_16x16x32_bf16
// C-tiles x 4 k-steps x 3 split terms. Fragment layout: A row = lane&15, k contiguous at
// (lane>>4)*8; B col = lane&15 (W rows = B^T); C col = lane&15, row = (lane>>4)*4+reg.
// LDS tiles [row][k] bf16 with byte_off ^= (row&7)<<4 swizzle (G4: row-major stride-256B
// fragment reads would otherwise serialize). sproj (epilogue tile) aliases the B region.
__global__ __launch_bounds__(256) void k_gemm_max(
    const float* __restrict__ feat, const unsigned short* __restrict__ Whi,
    const unsigned short* __restrict__ Wlo, const float* __restrict__ bias,
    const int* __restrict__ scode, const int* __restrict__ rank, const int* __restrict__ sorted,
    unsigned* __restrict__ xout, int N) {
    __shared__ __align__(16) char smem[65536];
    unsigned short* Ahi = (unsigned short*)smem;            // [64][128] bf16, swizzled, 16KB
    unsigned short* Alo = (unsigned short*)(smem + 16384);  // 16KB
    unsigned short* Bhi = (unsigned short*)(smem + 32768);  // [64][128] bf16, swizzled, 16KB
    unsigned short* Blo = (unsigned short*)(smem + 49152);  // 16KB
    float (*sproj)[68] = (float(*)[68])(smem + 32768);      // 17408B, aliases Bhi/Blo
    __shared__ int scid[64];
    __shared__ int sidx[64];
    int t = threadIdx.x;
    int rowbase = blockIdx.x * 64;
    if (t < 64) {
        int i = sorted[rowbase + t];
        sidx[t] = i;
        scid[t] = rank[scode[i] >> 3];
    }
    __syncthreads();
    // stage A: gathered fp32 rows -> bf16 hi/lo split, XOR-swizzled
#pragma unroll
    for (int j = 0; j < 8; j++) {
        int idx = t + 256 * j;
        int r = idx >> 5, c4 = idx & 31;
        float4 v = *(const float4*)(feat + (size_t)sidx[r] * 128 + c4 * 4);
        unsigned short h0 = bf16h(v.x), h1 = bf16h(v.y), h2 = bf16h(v.z), h3 = bf16h(v.w);
        float l0 = v.x - __uint_as_float((unsigned)h0 << 16);
        float l1 = v.y - __uint_as_float((unsigned)h1 << 16);
        float l2 = v.z - __uint_as_float((unsigned)h2 << 16);
        float l3 = v.w - __uint_as_float((unsigned)h3 << 16);
        int off = r * 256 + ((c4 * 8) ^ ((r & 7) << 4));
        *(ushort4*)((char*)Ahi + off) = make_ushort4(h0, h1, h2, h3);
        *(ushort4*)((char*)Alo + off) = make_ushort4(bf16h(l0), bf16h(l1), bf16h(l2), bf16h(l3));
    }
    int w = t >> 6, l = t & 63;
    int lr = l & 15, lg = l >> 4;
    int arow = w * 16 + lr;
    int abase = arow * 256;
    int aswz = (arow & 7) << 4;
    int q = w, ch = l;  // epilogue roles: wave q scans points [16q,16q+16) for channel ch
    for (int ct = 0; ct < 4; ct++) {
        __syncthreads();  // A staged / previous epilogue reads of sproj done
        // stage B-tile (64 ch x 128 k, hi+lo), coalesced 16B loads, swizzled writes
#pragma unroll
        for (int j = 0; j < 4; j++) {
            int idx = t + 256 * j;
            int r = idx >> 4, c16 = idx & 15;
            int goff = (ct * 64 + r) * 128 + c16 * 8;
            uint4 vh = *(const uint4*)(Whi + goff);
            uint4 vl = *(const uint4*)(Wlo + goff);
            int off = r * 256 + ((c16 * 16) ^ ((r & 7) << 4));
            *(uint4*)((char*)Bhi + off) = vh;
            *(uint4*)((char*)Blo + off) = vl;
        }
        __syncthreads();
        f32x4 acc[4];
#pragma unroll
        for (int tc = 0; tc < 4; tc++) acc[tc] = (f32x4){0.0f, 0.0f, 0.0f, 0.0f};
#pragma unroll
        for (int s = 0; s < 4; s++) {
            int ak = abase + ((s * 64 + lg * 16) ^ aswz);
            short8 ah = *(const short8*)((char*)Ahi + ak);
            short8 al = *(const short8*)((char*)Alo + ak);
#pragma unroll
            for (int tc = 0; tc < 4; tc++) {
                int brow = tc * 16 + lr;
                int bk = brow * 256 + ((s * 64 + lg * 16) ^ ((brow & 7) << 4));
                short8 bh = *(const short8*)((char*)Bhi + bk);
                short8 bl = *(const short8*)((char*)Blo + bk);
                acc[tc] = __builtin_amdgcn_mfma_f32_16x16x32_bf16(ah, bh, acc[tc], 0, 0, 0);
                acc[tc] = __builtin_amdgcn_mfma_f32_16x16x32_bf16(al, bh, acc[tc], 0, 0, 0);
                acc[tc] = __builtin_amdgcn_mfma_f32_16x16x32_bf16(ah, bl, acc[tc], 0, 0, 0);
            }
        }
        __syncthreads();  // all B-tile reads done -> sproj may overwrite the region
        // proj (+bias) -> sproj[point][ch_local]
#pragma unroll
        for (int tc = 0; tc < 4; tc++) {
            float bb = bias[ct * 64 + tc * 16 + lr];
#pragma unroll
            for (int r = 0; r < 4; r++) {
                sproj[w * 16 + lg * 4 + r][tc * 16 + lr] = acc[tc][r] + bb;
            }
        }
        __syncthreads();
        // segmented max over the sorted 64-point tile; run boundaries are wave-uniform.
        // Runs strictly inside a 16-point quarter are complete clusters -> plain store.
        {
            int p0 = q * 16;
            int cur = scid[p0];
            float mx = sproj[p0][ch];
            bool tstart = true;  // current run touches the quarter's start
            size_t choff = (size_t)(ct * 64 + ch);
            for (int p = 1; p < 16; p++) {
                int cid = scid[p0 + p];
                float v = sproj[p0 + p][ch];
                if (cid == cur) {
                    mx = fmaxf(mx, v);
                } else {
                    unsigned e = encf(mx);
                    if (tstart) atomicMax(&xout[(size_t)cur * 256 + choff], e);
                    else xout[(size_t)cur * 256 + choff] = e;
                    tstart = false;
                    cur = cid;
                    mx = v;
                }
            }
            // final run touches the quarter's end -> may continue into next quarter/block
            atomicMax(&xout[(size_t)cur * 256 + choff], encf(mx));
        }
    }
}

// K10: in-place LayerNorm + exact GELU over each cluster row (decode encoded maxes first).
__global__ __launch_bounds__(256) void k_ln_gelu(unsigned* __restrict__ x,
                                                 const float* __restrict__ gamma,
                                                 const float* __restrict__ beta, int M) {
    int row = blockIdx.x;
    if (row >= M) return;
    int t = threadIdx.x;
    float v = decf(x[(size_t)row * 256 + t]);
    float s = v, s2 = v * v;
#pragma unroll
    for (int off = 32; off > 0; off >>= 1) {
        s += __shfl_down(s, off);
        s2 += __shfl_down(s2, off);
    }
    __shared__ float red[8];
    int wave = t >> 6, lane = t & 63;
    if (lane == 0) { red[wave] = s; red[4 + wave] = s2; }
    __syncthreads();
    if (t == 0) {
        red[0] = red[0] + red[1] + red[2] + red[3];
        red[4] = red[4] + red[5] + red[6] + red[7];
    }
    __syncthreads();
    float mean = red[0] * (1.0f / 256.0f);
    float var = red[4] * (1.0f / 256.0f) - mean * mean;
    float xn = (v - mean) * rsqrtf(var + 1e-5f) * gamma[t] + beta[t];
    float g = 0.5f * xn * (1.0f + erff(xn * 0.70710678118654752f));
    ((float*)x)[(size_t)row * 256 + t] = g;
}

extern "C" void kernel_launch(void* const* d_in, const int* in_sizes, int n_in,
                              void* d_out, int out_size, void* d_ws, size_t ws_size,
                              hipStream_t stream) {
    const float* feat = (const float*)d_in[0];
    const float* coord = (const float*)d_in[1];
    const int* grid_coord = (const int*)d_in[2];
    const int* scode = (const int*)d_in[3];   // int32 (JAX x64-off truncation), shape (2,N)
    const int* batch = (const int*)d_in[4];
    const float* W = (const float*)d_in[6];
    const float* bias = (const float*)d_in[7];
    const float* gamma = (const float*)d_in[8];
    const float* beta = (const float*)d_in[9];

    int N = in_sizes[0] / 128;                 // C_IN = 128
    int M = (out_size - N) / 269;              // 269 = 256+3+3+2+2+2+1 per-cluster elems

    float* out = (float*)d_out;
    float* x_out = out;                        // M*256
    float* coord_p = x_out + (size_t)M * 256;  // 3M
    float* grid_p = coord_p + (size_t)3 * M;   // 3M
    float* code_h = grid_p + (size_t)3 * M;    // 2M
    float* order = code_h + (size_t)2 * M;     // 2M
    float* inverse = order + (size_t)2 * M;    // 2M
    float* cluster = inverse + (size_t)2 * M;  // N
    float* batch_p = cluster + (size_t)N;      // M

    int* head_min = (int*)d_ws;        // NBINS  (reused: fill counters, then W hi/lo bf16)
    int* cnt = head_min + NBINS;       // NBINS  (reused as per-bin segment starts)
    int* rank = cnt + NBINS;           // NBINS
    int* hist2 = rank + NBINS;         // NBINS
    int* fill2 = hist2 + NBINS;        // NBINS
    int* heads = fill2 + NBINS;        // M
    int* countsC = heads + M;          // M
    float* coordsum = (float*)(countsC + M);       // 3M
    int* keys = (int*)(coordsum + (size_t)3 * M);  // M
    int* sorted = keys + M;                        // N (cluster-sorted point permutation)
    // W hi/lo splits alias the head_min region (dead after k_points): 128KB <= 512KB
    unsigned short* Whi = (unsigned short*)head_min;  // 32768 ushort
    unsigned short* Wlo = Whi + 32768;                // 32768 ushort

    hipMemsetAsync(head_min, 0x7F, (size_t)NBINS * sizeof(int), stream);      // "+inf" index
    hipMemsetAsync(cnt, 0, (size_t)4 * NBINS * sizeof(int), stream);          // cnt,rank,hist2,fill2
    hipMemsetAsync(coordsum, 0, (size_t)3 * M * sizeof(float), stream);
    hipMemsetAsync(x_out, 0, (size_t)M * 256 * sizeof(float), stream);        // encoded -inf

    k_hist<<<(N + 255) / 256, 256, 0, stream>>>(scode, head_min, cnt, N);
    k_scan_compact<<<1, 1024, 0, stream>>>(cnt, head_min, rank, heads, countsC);
    k_points<<<(N + 255) / 256, 256, 0, stream>>>(scode, rank, cnt, head_min, coord, cluster,
                                                  coordsum, sorted, N);
    k_wsplit<<<128, 256, 0, stream>>>(W, Whi, Wlo);  // head_min region is dead now
    k_clusters<<<(M + 255) / 256, 256, 0, stream>>>(scode, batch, grid_coord, heads, countsC,
                                                    coordsum, coord_p, grid_p, code_h, order,
                                                    inverse, batch_p, hist2, M, N);
    k_scan_excl<<<1, 1024, 0, stream>>>(hist2);
    k_keys<<<(M + 255) / 256, 256, 0, stream>>>(scode, heads, hist2, fill2, keys, M, N);
    k_bsort<<<NBINS / 256, 256, 0, stream>>>(keys, hist2, fill2);
    k_orders<<<(M + 255) / 256, 256, 0, stream>>>(keys, order + M, inverse + M, M);
    k_gemm_max<<<N / 64, 256, 0, stream>>>(feat, Whi, Wlo, bias, scode, rank, sorted,
                                           (unsigned*)x_out, N);
    k_ln_gelu<<<M, 256, 0, stream>>>((unsigned*)x_out, gamma, beta, M);
}

// Round 6
// 1624.289 us; speedup vs baseline: 3.2010x; 1.3864x over previous
//
#include <hip/hip_runtime.h>
#include <math.h>

#define NBINS 131072

typedef __attribute__((ext_vector_type(8))) short short8;
typedef __attribute__((ext_vector_type(4))) float f32x4;

// ---- order-preserving float<->u32 encoding for atomicMax on floats ----
__device__ __forceinline__ unsigned encf(float f) {
    unsigned u = __float_as_uint(f);
    return (u & 0x80000000u) ? ~u : (u | 0x80000000u);
}
__device__ __forceinline__ float decf(unsigned u) {
    return (u & 0x80000000u) ? __uint_as_float(u & 0x7FFFFFFFu) : __uint_as_float(~u);
}
// RNE fp32 -> bf16 (upper 16 bits)
__device__ __forceinline__ unsigned short bf16h(float f) {
    unsigned u = __float_as_uint(f);
    return (unsigned short)((u + 0x7FFFu + ((u >> 16) & 1u)) >> 16);
}

// K1: per-bin count + min-index (head) over all N points. c0 = code0 >> 3 < 2^17.
__global__ void k_hist(const int* __restrict__ scode, int* head_min, int* cnt, int N) {
    int i = blockIdx.x * blockDim.x + threadIdx.x;
    if (i >= N) return;
    int c0 = scode[i] >> 3;
    atomicMin(&head_min[c0], i);
    atomicAdd(&cnt[c0], 1);
}

// ---- multi-block scan over the 2^17 bins (replaces the 595us single-block scan) ----
// Phase 1: per-block (256 bins) presence+count sums.
__global__ void k_scanA_part(const int* __restrict__ cnt, int* partp, int* partc) {
    int t = threadIdx.x;
    int v = blockIdx.x * 256 + t;
    int c = cnt[v];
    int p = (c > 0);
    __shared__ int sp[256], sq[256];
    sp[t] = p; sq[t] = c;
    __syncthreads();
    for (int off = 1; off < 256; off <<= 1) {
        int vp = (t >= off) ? sp[t - off] : 0;
        int vq = (t >= off) ? sq[t - off] : 0;
        __syncthreads();
        sp[t] += vp; sq[t] += vq;
        __syncthreads();
    }
    if (t == 255) { partp[blockIdx.x] = sp[255]; partc[blockIdx.x] = sq[255]; }
}

// Phase 2: exclusive scan of the 512 partials (both arrays), single small block.
__global__ void k_scanA_mid(int* partp, int* partc) {
    int t = threadIdx.x;  // 512
    __shared__ int sp[512], sq[512];
    int p = partp[t], c = partc[t];
    sp[t] = p; sq[t] = c;
    __syncthreads();
    for (int off = 1; off < 512; off <<= 1) {
        int vp = (t >= off) ? sp[t - off] : 0;
        int vq = (t >= off) ? sq[t - off] : 0;
        __syncthreads();
        sp[t] += vp; sq[t] += vq;
        __syncthreads();
    }
    partp[t] = sp[t] - p;  // exclusive
    partc[t] = sq[t] - c;
}

// Phase 3: block-local exclusive scan + block base; write compacted outputs.
// Same semantics as the old k_scan_compact: for nonempty bin v (in increasing v):
//   rank[v]=rp; heads[rp]=head_min[v]; countsC[rp]=cnt[v]; cnt[v]=rc(binstart); head_min[v]=0.
__global__ void k_scanA_write(int* cnt, int* head_min, int* rank, int* heads, int* countsC,
                              const int* __restrict__ partp, const int* __restrict__ partc) {
    int t = threadIdx.x;
    int b = blockIdx.x;
    int v = b * 256 + t;
    int c = cnt[v];
    int p = (c > 0);
    __shared__ int sp[256], sq[256];
    sp[t] = p; sq[t] = c;
    __syncthreads();
    for (int off = 1; off < 256; off <<= 1) {
        int vp = (t >= off) ? sp[t - off] : 0;
        int vq = (t >= off) ? sq[t - off] : 0;
        __syncthreads();
        sp[t] += vp; sq[t] += vq;
        __syncthreads();
    }
    if (c > 0) {
        int rp = sp[t] - p + partp[b];
        int rc = sq[t] - c + partc[b];
        rank[v] = rp;
        heads[rp] = head_min[v];
        countsC[rp] = c;
        cnt[v] = rc;       // binstart (alias)
        head_min[v] = 0;   // fill3 init (alias)
    }
}

// ---- multi-block in-place exclusive scan for hist2 (replaces k_scan_excl) ----
__global__ void k_scanB_part(const int* __restrict__ a, int* part2) {
    int t = threadIdx.x;
    int v = blockIdx.x * 256 + t;
    int c = a[v];
    __shared__ int sq[256];
    sq[t] = c;
    __syncthreads();
    for (int off = 1; off < 256; off <<= 1) {
        int vq = (t >= off) ? sq[t - off] : 0;
        __syncthreads();
        sq[t] += vq;
        __syncthreads();
    }
    if (t == 255) part2[blockIdx.x] = sq[255];
}

__global__ void k_scanB_mid(int* part2) {
    int t = threadIdx.x;  // 512
    __shared__ int sq[512];
    int c = part2[t];
    sq[t] = c;
    __syncthreads();
    for (int off = 1; off < 512; off <<= 1) {
        int vq = (t >= off) ? sq[t - off] : 0;
        __syncthreads();
        sq[t] += vq;
        __syncthreads();
    }
    part2[t] = sq[t] - c;  // exclusive
}

__global__ void k_scanB_write(int* a, const int* __restrict__ part2) {
    int t = threadIdx.x;
    int b = blockIdx.x;
    int v = b * 256 + t;
    int c = a[v];
    __shared__ int sq[256];
    sq[t] = c;
    __syncthreads();
    for (int off = 1; off < 256; off <<= 1) {
        int vq = (t >= off) ? sq[t - off] : 0;
        __syncthreads();
        sq[t] += vq;
        __syncthreads();
    }
    a[v] = sq[t] - c + part2[b];
}

// K3: per-point cluster id output + coord sums (atomics) + cluster-sorted scatter.
__global__ void k_points(const int* __restrict__ scode, const int* __restrict__ rank,
                         const int* __restrict__ binstart, int* fill3,
                         const float* __restrict__ coord, float* __restrict__ cluster_out,
                         float* __restrict__ coordsum, int* __restrict__ sorted, int N) {
    int i = blockIdx.x * blockDim.x + threadIdx.x;
    if (i >= N) return;
    int bin = scode[i] >> 3;
    int m = rank[bin];
    cluster_out[i] = (float)m;
    int pos = binstart[bin] + atomicAdd(&fill3[bin], 1);
    sorted[pos] = i;
    atomicAdd(&coordsum[m * 3 + 0], coord[(size_t)i * 3 + 0]);
    atomicAdd(&coordsum[m * 3 + 1], coord[(size_t)i * 3 + 1]);
    atomicAdd(&coordsum[m * 3 + 2], coord[(size_t)i * 3 + 2]);
}

// K3b: split W (256x128 fp32) into bf16 hi/lo for the Markidis 3-term MFMA GEMM.
// Whi/Wlo live in the dead head_min workspace region (free after k_points).
__global__ void k_wsplit(const float* __restrict__ W, unsigned short* __restrict__ Whi,
                         unsigned short* __restrict__ Wlo) {
    int i = blockIdx.x * blockDim.x + threadIdx.x;  // 32768 = 256*128
    float f = W[i];
    unsigned short h = bf16h(f);
    float hf = __uint_as_float((unsigned)h << 16);
    Whi[i] = h;
    Wlo[i] = bf16h(f - hf);
}

// K4: per-cluster small outputs + histogram of c1 buckets for the row-1 sort.
__global__ void k_clusters(const int* __restrict__ scode, const int* __restrict__ batch,
                           const int* __restrict__ grid_coord, const int* __restrict__ heads,
                           const int* __restrict__ countsC, const float* __restrict__ coordsum,
                           float* __restrict__ coord_p, float* __restrict__ grid_p,
                           float* __restrict__ code_h, float* __restrict__ order,
                           float* __restrict__ inverse, float* __restrict__ batch_p,
                           int* hist2, int M, int N) {
    int m = blockIdx.x * blockDim.x + threadIdx.x;
    if (m >= M) return;
    int h = heads[m];
    float invc = 1.0f / (float)countsC[m];
    coord_p[m * 3 + 0] = coordsum[m * 3 + 0] * invc;
    coord_p[m * 3 + 1] = coordsum[m * 3 + 1] * invc;
    coord_p[m * 3 + 2] = coordsum[m * 3 + 2] * invc;
    grid_p[m * 3 + 0] = (float)(grid_coord[(size_t)h * 3 + 0] >> 1);
    grid_p[m * 3 + 1] = (float)(grid_coord[(size_t)h * 3 + 1] >> 1);
    grid_p[m * 3 + 2] = (float)(grid_coord[(size_t)h * 3 + 2] >> 1);
    int c1 = scode[N + h] >> 3;
    code_h[m] = (float)(scode[h] >> 3);
    code_h[M + m] = (float)c1;
    // row 0 of code_h is strictly increasing in m -> order/inverse row 0 are identity
    order[m] = (float)m;
    inverse[m] = (float)m;
    batch_p[m] = (float)batch[h];
    atomicAdd(&hist2[c1 >> 10], 1);
}

// K6: scatter (c1_low<<17 | m) keys into buckets (bucket = c1>>10).
__global__ void k_keys(const int* __restrict__ scode, const int* __restrict__ heads,
                       const int* __restrict__ start, int* fill2, int* keys, int M, int N) {
    int m = blockIdx.x * blockDim.x + threadIdx.x;
    if (m >= M) return;
    int c1 = scode[N + heads[m]] >> 3;
    int b = c1 >> 10;
    int pos = start[b] + atomicAdd(&fill2[b], 1);
    keys[pos] = ((c1 & 1023) << 17) | m;
}

// K7: per-bucket insertion sort (bucket sizes ~Poisson(1), max ~10).
__global__ void k_bsort(int* keys, const int* __restrict__ start, const int* __restrict__ sz) {
    int b = blockIdx.x * blockDim.x + threadIdx.x;
    if (b >= NBINS) return;
    int s = start[b], n = sz[b];
    for (int i = 1; i < n; i++) {
        int k = keys[s + i];
        int j = i - 1;
        while (j >= 0 && keys[s + j] > k) { keys[s + j + 1] = keys[s + j]; j--; }
        keys[s + j + 1] = k;
    }
}

// K8: extract order row 1 and its inverse permutation.
__global__ void k_orders(const int* __restrict__ keys, float* __restrict__ order1,
                         float* __restrict__ inverse1, int M) {
    int i = blockIdx.x * blockDim.x + threadIdx.x;
    if (i >= M) return;
    int m = keys[i] & 0x1FFFF;
    order1[i] = (float)m;
    inverse1[m] = (float)i;
}

// K9: split-bf16 MFMA GEMM (proj = feat @ W^T + b as hi*hi + hi*lo + lo*hi, fp32 accum)
// over CLUSTER-SORTED points, fused with the segmented-max epilogue.
// Block: 64 points x 256 channels (4 serial 64-ch tiles), 256 threads = 4 waves.
__global__ __launch_bounds__(256) void k_gemm_max(
    const float* __restrict__ feat, const unsigned short* __restrict__ Whi,
    const unsigned short* __restrict__ Wlo, const float* __restrict__ bias,
    const int* __restrict__ scode, const int* __restrict__ rank, const int* __restrict__ sorted,
    unsigned* __restrict__ xout, int N) {
    __shared__ __align__(16) char smem[65536];
    unsigned short* Ahi = (unsigned short*)smem;            // [64][128] bf16, swizzled, 16KB
    unsigned short* Alo = (unsigned short*)(smem + 16384);  // 16KB
    unsigned short* Bhi = (unsigned short*)(smem + 32768);  // [64][128] bf16, swizzled, 16KB
    unsigned short* Blo = (unsigned short*)(smem + 49152);  // 16KB
    float (*sproj)[68] = (float(*)[68])(smem + 32768);      // 17408B, aliases Bhi/Blo
    __shared__ int scid[64];
    __shared__ int sidx[64];
    int t = threadIdx.x;
    int rowbase = blockIdx.x * 64;
    if (t < 64) {
        int i = sorted[rowbase + t];
        sidx[t] = i;
        scid[t] = rank[scode[i] >> 3];
    }
    __syncthreads();
    // stage A: gathered fp32 rows -> bf16 hi/lo split, XOR-swizzled
#pragma unroll
    for (int j = 0; j < 8; j++) {
        int idx = t + 256 * j;
        int r = idx >> 5, c4 = idx & 31;
        float4 v = *(const float4*)(feat + (size_t)sidx[r] * 128 + c4 * 4);
        unsigned short h0 = bf16h(v.x), h1 = bf16h(v.y), h2 = bf16h(v.z), h3 = bf16h(v.w);
        float l0 = v.x - __uint_as_float((unsigned)h0 << 16);
        float l1 = v.y - __uint_as_float((unsigned)h1 << 16);
        float l2 = v.z - __uint_as_float((unsigned)h2 << 16);
        float l3 = v.w - __uint_as_float((unsigned)h3 << 16);
        int off = r * 256 + ((c4 * 8) ^ ((r & 7) << 4));
        *(ushort4*)((char*)Ahi + off) = make_ushort4(h0, h1, h2, h3);
        *(ushort4*)((char*)Alo + off) = make_ushort4(bf16h(l0), bf16h(l1), bf16h(l2), bf16h(l3));
    }
    int w = t >> 6, l = t & 63;
    int lr = l & 15, lg = l >> 4;
    int arow = w * 16 + lr;
    int abase = arow * 256;
    int aswz = (arow & 7) << 4;
    int q = w, ch = l;  // epilogue roles: wave q scans points [16q,16q+16) for channel ch
    for (int ct = 0; ct < 4; ct++) {
        __syncthreads();  // A staged / previous epilogue reads of sproj done
        // stage B-tile (64 ch x 128 k, hi+lo), coalesced 16B loads, swizzled writes
#pragma unroll
        for (int j = 0; j < 4; j++) {
            int idx = t + 256 * j;
            int r = idx >> 4, c16 = idx & 15;
            int goff = (ct * 64 + r) * 128 + c16 * 8;
            uint4 vh = *(const uint4*)(Whi + goff);
            uint4 vl = *(const uint4*)(Wlo + goff);
            int off = r * 256 + ((c16 * 16) ^ ((r & 7) << 4));
            *(uint4*)((char*)Bhi + off) = vh;
            *(uint4*)((char*)Blo + off) = vl;
        }
        __syncthreads();
        f32x4 acc[4];
#pragma unroll
        for (int tc = 0; tc < 4; tc++) acc[tc] = (f32x4){0.0f, 0.0f, 0.0f, 0.0f};
#pragma unroll
        for (int s = 0; s < 4; s++) {
            int ak = abase + ((s * 64 + lg * 16) ^ aswz);
            short8 ah = *(const short8*)((char*)Ahi + ak);
            short8 al = *(const short8*)((char*)Alo + ak);
#pragma unroll
            for (int tc = 0; tc < 4; tc++) {
                int brow = tc * 16 + lr;
                int bk = brow * 256 + ((s * 64 + lg * 16) ^ ((brow & 7) << 4));
                short8 bh = *(const short8*)((char*)Bhi + bk);
                short8 bl = *(const short8*)((char*)Blo + bk);
                acc[tc] = __builtin_amdgcn_mfma_f32_16x16x32_bf16(ah, bh, acc[tc], 0, 0, 0);
                acc[tc] = __builtin_amdgcn_mfma_f32_16x16x32_bf16(al, bh, acc[tc], 0, 0, 0);
                acc[tc] = __builtin_amdgcn_mfma_f32_16x16x32_bf16(ah, bl, acc[tc], 0, 0, 0);
            }
        }
        __syncthreads();  // all B-tile reads done -> sproj may overwrite the region
        // proj (+bias) -> sproj[point][ch_local]
#pragma unroll
        for (int tc = 0; tc < 4; tc++) {
            float bb = bias[ct * 64 + tc * 16 + lr];
#pragma unroll
            for (int r = 0; r < 4; r++) {
                sproj[w * 16 + lg * 4 + r][tc * 16 + lr] = acc[tc][r] + bb;
            }
        }
        __syncthreads();
        // segmented max over the sorted 64-point tile; run boundaries are wave-uniform.
        // Runs strictly inside a 16-point quarter are complete clusters -> plain store.
        {
            int p0 = q * 16;
            int cur = scid[p0];
            float mx = sproj[p0][ch];
            bool tstart = true;  // current run touches the quarter's start
            size_t choff = (size_t)(ct * 64 + ch);
            for (int p = 1; p < 16; p++) {
                int cid = scid[p0 + p];
                float v = sproj[p0 + p][ch];
                if (cid == cur) {
                    mx = fmaxf(mx, v);
                } else {
                    unsigned e = encf(mx);
                    if (tstart) atomicMax(&xout[(size_t)cur * 256 + choff], e);
                    else xout[(size_t)cur * 256 + choff] = e;
                    tstart = false;
                    cur = cid;
                    mx = v;
                }
            }
            // final run touches the quarter's end -> may continue into next quarter/block
            atomicMax(&xout[(size_t)cur * 256 + choff], encf(mx));
        }
    }
}

// K10: in-place LayerNorm + exact GELU over each cluster row (decode encoded maxes first).
__global__ __launch_bounds__(256) void k_ln_gelu(unsigned* __restrict__ x,
                                                 const float* __restrict__ gamma,
                                                 const float* __restrict__ beta, int M) {
    int row = blockIdx.x;
    if (row >= M) return;
    int t = threadIdx.x;
    float v = decf(x[(size_t)row * 256 + t]);
    float s = v, s2 = v * v;
#pragma unroll
    for (int off = 32; off > 0; off >>= 1) {
        s += __shfl_down(s, off);
        s2 += __shfl_down(s2, off);
    }
    __shared__ float red[8];
    int wave = t >> 6, lane = t & 63;
    if (lane == 0) { red[wave] = s; red[4 + wave] = s2; }
    __syncthreads();
    if (t == 0) {
        red[0] = red[0] + red[1] + red[2] + red[3];
        red[4] = red[4] + red[5] + red[6] + red[7];
    }
    __syncthreads();
    float mean = red[0] * (1.0f / 256.0f);
    float var = red[4] * (1.0f / 256.0f) - mean * mean;
    float xn = (v - mean) * rsqrtf(var + 1e-5f) * gamma[t] + beta[t];
    float g = 0.5f * xn * (1.0f + erff(xn * 0.70710678118654752f));
    ((float*)x)[(size_t)row * 256 + t] = g;
}

extern "C" void kernel_launch(void* const* d_in, const int* in_sizes, int n_in,
                              void* d_out, int out_size, void* d_ws, size_t ws_size,
                              hipStream_t stream) {
    const float* feat = (const float*)d_in[0];
    const float* coord = (const float*)d_in[1];
    const int* grid_coord = (const int*)d_in[2];
    const int* scode = (const int*)d_in[3];   // int32 (JAX x64-off truncation), shape (2,N)
    const int* batch = (const int*)d_in[4];
    const float* W = (const float*)d_in[6];
    const float* bias = (const float*)d_in[7];
    const float* gamma = (const float*)d_in[8];
    const float* beta = (const float*)d_in[9];

    int N = in_sizes[0] / 128;                 // C_IN = 128
    int M = (out_size - N) / 269;              // 269 = 256+3+3+2+2+2+1 per-cluster elems

    float* out = (float*)d_out;
    float* x_out = out;                        // M*256
    float* coord_p = x_out + (size_t)M * 256;  // 3M
    float* grid_p = coord_p + (size_t)3 * M;   // 3M
    float* code_h = grid_p + (size_t)3 * M;    // 2M
    float* order = code_h + (size_t)2 * M;     // 2M
    float* inverse = order + (size_t)2 * M;    // 2M
    float* cluster = inverse + (size_t)2 * M;  // N
    float* batch_p = cluster + (size_t)N;      // M

    int* head_min = (int*)d_ws;        // NBINS  (reused: fill counters, then W hi/lo bf16)
    int* cnt = head_min + NBINS;       // NBINS  (reused as per-bin segment starts)
    int* rank = cnt + NBINS;           // NBINS
    int* hist2 = rank + NBINS;         // NBINS
    int* fill2 = hist2 + NBINS;        // NBINS
    int* heads = fill2 + NBINS;        // M
    int* countsC = heads + M;          // M
    float* coordsum = (float*)(countsC + M);       // 3M
    int* keys = (int*)(coordsum + (size_t)3 * M);  // M
    int* sorted = keys + M;                        // N (cluster-sorted point permutation)
    int* partp = sorted + N;                       // 512 scan partials
    int* partc = partp + 512;                      // 512
    int* part2 = partc + 512;                      // 512
    // W hi/lo splits alias the head_min region (dead after k_points): 128KB <= 512KB
    unsigned short* Whi = (unsigned short*)head_min;  // 32768 ushort
    unsigned short* Wlo = Whi + 32768;                // 32768 ushort

    hipMemsetAsync(head_min, 0x7F, (size_t)NBINS * sizeof(int), stream);      // "+inf" index
    hipMemsetAsync(cnt, 0, (size_t)4 * NBINS * sizeof(int), stream);          // cnt,rank,hist2,fill2
    hipMemsetAsync(coordsum, 0, (size_t)3 * M * sizeof(float), stream);
    hipMemsetAsync(x_out, 0, (size_t)M * 256 * sizeof(float), stream);        // encoded -inf

    k_hist<<<(N + 255) / 256, 256, 0, stream>>>(scode, head_min, cnt, N);
    k_scanA_part<<<NBINS / 256, 256, 0, stream>>>(cnt, partp, partc);
    k_scanA_mid<<<1, 512, 0, stream>>>(partp, partc);
    k_scanA_write<<<NBINS / 256, 256, 0, stream>>>(cnt, head_min, rank, heads, countsC,
                                                   partp, partc);
    k_points<<<(N + 255) / 256, 256, 0, stream>>>(scode, rank, cnt, head_min, coord, cluster,
                                                  coordsum, sorted, N);
    k_wsplit<<<128, 256, 0, stream>>>(W, Whi, Wlo);  // head_min region is dead now
    k_clusters<<<(M + 255) / 256, 256, 0, stream>>>(scode, batch, grid_coord, heads, countsC,
                                                    coordsum, coord_p, grid_p, code_h, order,
                                                    inverse, batch_p, hist2, M, N);
    k_scanB_part<<<NBINS / 256, 256, 0, stream>>>(hist2, part2);
    k_scanB_mid<<<1, 512, 0, stream>>>(part2);
    k_scanB_write<<<NBINS / 256, 256, 0, stream>>>(hist2, part2);
    k_keys<<<(M + 255) / 256, 256, 0, stream>>>(scode, heads, hist2, fill2, keys, M, N);
    k_bsort<<<NBINS / 256, 256, 0, stream>>>(keys, hist2, fill2);
    k_orders<<<(M + 255) / 256, 256, 0, stream>>>(keys, order + M, inverse + M, M);
    k_gemm_max<<<N / 64, 256, 0, stream>>>(feat, Whi, Wlo, bias, scode, rank, sorted,
                                           (unsigned*)x_out, N);
    k_ln_gelu<<<M, 256, 0, stream>>>((unsigned*)x_out, gamma, beta, M);
}